// Round 1
// baseline (1093.142 us; speedup 1.0000x reference)
//
#include <hip/hip_runtime.h>
#include <hip/hip_bf16.h>
#include <math.h>

// SGC: out = log_softmax( S^2 X W^T + b ), S = D^-1/2 (A+I) D^-1/2
// Strategy: transform first (X W^T -> 40 dims), build CSR (by dst) once,
// gather-based propagation x2, then bias + log_softmax.

#define N_NODES 100000
#define N_FEAT  128
#define N_CLASS 40

// ---------------------------------------------------------------------------
// Edge-index access: harness may hand us int32 or raw int64 words.
// If int64 (little-endian, values < 2^31), every odd 32-bit word is 0.
__global__ void detect_kernel(const int* __restrict__ ei, int* __restrict__ flag) {
    int lane = threadIdx.x;                 // 64 threads, 1 wave
    int nz = (ei[2 * lane + 1] != 0) ? 1 : 0;
    unsigned long long b = __ballot(nz);
    if (lane == 0) *flag = (b == 0ull) ? 1 : 0;   // 1 => int64 layout
}

__device__ __forceinline__ int edge_word(const int* ei, int elem, int is64) {
    return is64 ? ei[2 * elem] : ei[elem];
}

// ---------------------------------------------------------------------------
__global__ void zero_deg_kernel(int* __restrict__ deg, int n) {
    int i = blockIdx.x * blockDim.x + threadIdx.x;
    if (i < n) deg[i] = 0;
}

__global__ void count_kernel(const int* __restrict__ ei, int E,
                             const int* __restrict__ flag, int* __restrict__ deg) {
    int e = blockIdx.x * blockDim.x + threadIdx.x;
    if (e >= E) return;
    int is64 = *flag;
    int c = edge_word(ei, E + e, is64);     // col (target) of edge e
    atomicAdd(&deg[c], 1);
}

// Single-block hierarchical exclusive scan over deg[N]; also emits
// cursor (copy of starts) and dis = rsqrt(deg+1) (self-loop included).
__global__ __launch_bounds__(1024) void scan_kernel(
    const int* __restrict__ deg, int* __restrict__ starts, int* __restrict__ cursor,
    float* __restrict__ dis, int N)
{
    __shared__ int wsum[16];
    __shared__ int ctot;
    int t = threadIdx.x, lane = t & 63, wid = t >> 6;
    int base = 0;
    int nchunk = (N + 4095) / 4096;
    for (int ch = 0; ch < nchunk; ++ch) {
        int i0 = ch * 4096 + t * 4;
        int v0 = 0, v1 = 0, v2 = 0, v3 = 0;
        if (i0 + 3 < N) {
            int4 v = *reinterpret_cast<const int4*>(deg + i0);
            v0 = v.x; v1 = v.y; v2 = v.z; v3 = v.w;
        } else {
            if (i0     < N) v0 = deg[i0];
            if (i0 + 1 < N) v1 = deg[i0 + 1];
            if (i0 + 2 < N) v2 = deg[i0 + 2];
            if (i0 + 3 < N) v3 = deg[i0 + 3];
        }
        int tsum = v0 + v1 + v2 + v3;
        // inclusive wave scan of per-thread sums
        int x = tsum;
        #pragma unroll
        for (int o = 1; o < 64; o <<= 1) {
            int y = __shfl_up(x, o, 64);
            if (lane >= o) x += y;
        }
        if (lane == 63) wsum[wid] = x;
        __syncthreads();
        if (wid == 0 && lane < 16) {
            int ws = wsum[lane];
            int xs = ws;
            #pragma unroll
            for (int o = 1; o < 16; o <<= 1) {
                int y = __shfl_up(xs, o, 64);
                if (lane >= o) xs += y;
            }
            wsum[lane] = xs - ws;           // exclusive wave offsets
            if (lane == 15) ctot = xs;      // chunk total
        }
        __syncthreads();
        int p = base + wsum[wid] + (x - tsum);  // exclusive prefix, first elem
        if (i0     < N) { starts[i0]   = p; cursor[i0]   = p; dis[i0]   = rsqrtf((float)(v0 + 1)); p += v0; }
        if (i0 + 1 < N) { starts[i0+1] = p; cursor[i0+1] = p; dis[i0+1] = rsqrtf((float)(v1 + 1)); p += v1; }
        if (i0 + 2 < N) { starts[i0+2] = p; cursor[i0+2] = p; dis[i0+2] = rsqrtf((float)(v2 + 1)); p += v2; }
        if (i0 + 3 < N) { starts[i0+3] = p; cursor[i0+3] = p; dis[i0+3] = rsqrtf((float)(v3 + 1)); p += v3; }
        base += ctot;
        __syncthreads();                    // protect wsum/ctot for next chunk
    }
    if (t == 0) starts[N] = base;
}

__global__ void scatter_kernel(const int* __restrict__ ei, int E,
                               const int* __restrict__ flag,
                               int* __restrict__ cursor, int* __restrict__ srcs) {
    int e = blockIdx.x * blockDim.x + threadIdx.x;
    if (e >= E) return;
    int is64 = *flag;
    int r = edge_word(ei, e, is64);         // row (source)
    int c = edge_word(ei, E + e, is64);     // col (target)
    int pos = atomicAdd(&cursor[c], 1);
    srcs[pos] = r;
}

// ---------------------------------------------------------------------------
// y0 = X @ W^T  (one wave per node; W transposed into LDS)
__global__ __launch_bounds__(256) void transform_kernel(
    const float* __restrict__ x, const float* __restrict__ W,
    float* __restrict__ y, int N)
{
    __shared__ float Wt[N_FEAT * N_CLASS];  // Wt[f*40 + c], 20 KiB
    for (int i = threadIdx.x; i < N_FEAT * N_CLASS; i += blockDim.x) {
        int cls = i / N_FEAT, f = i % N_FEAT;
        Wt[f * N_CLASS + cls] = W[i];
    }
    __syncthreads();
    int wave = (blockIdx.x * blockDim.x + threadIdx.x) >> 6;
    int lane = threadIdx.x & 63;
    if (wave >= N) return;
    int cc = lane < N_CLASS ? lane : N_CLASS - 1;   // clamp idle lanes (broadcast)
    const float4* xr = reinterpret_cast<const float4*>(x + (size_t)wave * N_FEAT);
    float acc = 0.f;
    #pragma unroll
    for (int f4 = 0; f4 < N_FEAT / 4; ++f4) {
        float4 v = xr[f4];                  // wave-uniform address -> broadcast
        int f = f4 * 4;
        acc += v.x * Wt[(f    ) * N_CLASS + cc];
        acc += v.y * Wt[(f + 1) * N_CLASS + cc];
        acc += v.z * Wt[(f + 2) * N_CLASS + cc];
        acc += v.w * Wt[(f + 3) * N_CLASS + cc];
    }
    if (lane < N_CLASS) y[(size_t)wave * N_CLASS + lane] = acc;
}

// One propagation hop: yout[d] = dis[d] * sum_{e:col=d} dis[src]*yin[src] + dis[d]^2*yin[d]
__global__ __launch_bounds__(256) void prop_kernel(
    const float* __restrict__ yin, float* __restrict__ yout,
    const int* __restrict__ starts, const int* __restrict__ srcs,
    const float* __restrict__ dis, int N)
{
    int wave = (blockIdx.x * blockDim.x + threadIdx.x) >> 6;
    int lane = threadIdx.x & 63;
    if (wave >= N) return;
    int d = wave;
    int cc = lane < N_CLASS ? lane : N_CLASS - 1;
    float dd = dis[d];
    float self = yin[(size_t)d * N_CLASS + cc];
    int e = starts[d], e1 = starts[d + 1];
    float acc = 0.f;
    // unroll by 2 for a little ILP
    for (; e + 1 < e1; e += 2) {
        int sa = srcs[e], sb = srcs[e + 1];
        float wa = dis[sa], wb = dis[sb];
        float xa = yin[(size_t)sa * N_CLASS + cc];
        float xb = yin[(size_t)sb * N_CLASS + cc];
        acc += wa * xa;
        acc += wb * xb;
    }
    if (e < e1) {
        int sa = srcs[e];
        acc += dis[sa] * yin[(size_t)sa * N_CLASS + cc];
    }
    if (lane < N_CLASS)
        yout[(size_t)d * N_CLASS + lane] = dd * acc + dd * dd * self;
}

// out = log_softmax(y + bias) per node (one wave per node)
__global__ __launch_bounds__(256) void final_kernel(
    const float* __restrict__ y, const float* __restrict__ bias,
    float* __restrict__ out, int N)
{
    int wave = (blockIdx.x * blockDim.x + threadIdx.x) >> 6;
    int lane = threadIdx.x & 63;
    if (wave >= N) return;
    float v = (lane < N_CLASS) ? (y[(size_t)wave * N_CLASS + lane] + bias[lane]) : -INFINITY;
    float m = v;
    #pragma unroll
    for (int o = 32; o; o >>= 1) m = fmaxf(m, __shfl_xor(m, o, 64));
    float ex = (lane < N_CLASS) ? expf(v - m) : 0.f;
    float s = ex;
    #pragma unroll
    for (int o = 32; o; o >>= 1) s += __shfl_xor(s, o, 64);
    if (lane < N_CLASS)
        out[(size_t)wave * N_CLASS + lane] = v - m - logf(s);
}

// ---------------------------------------------------------------------------
extern "C" void kernel_launch(void* const* d_in, const int* in_sizes, int n_in,
                              void* d_out, int out_size, void* d_ws, size_t ws_size,
                              hipStream_t stream) {
    const float* feature = (const float*)d_in[0];   // [N, 128]
    const float* weight  = (const float*)d_in[1];   // [40, 128]
    const float* bias    = (const float*)d_in[2];   // [40]
    const int*   ei      = (const int*)d_in[3];     // [2, E] (int32 or int64 words)
    const int N = N_NODES;
    const int E = in_sizes[3] / 2;

    // workspace carve-up (256B-aligned regions)
    size_t off = 0;
    auto take = [&](size_t bytes) { size_t o = off; off += (bytes + 255) & ~(size_t)255; return o; };
    char* ws = (char*)d_ws;
    int*   flag   = (int*)  (ws + take(4));
    int*   deg    = (int*)  (ws + take((size_t)N * 4));
    int*   starts = (int*)  (ws + take((size_t)(N + 1) * 4));
    int*   cursor = (int*)  (ws + take((size_t)N * 4));
    int*   srcs   = (int*)  (ws + take((size_t)E * 4));
    float* dis    = (float*)(ws + take((size_t)N * 4));
    float* ya     = (float*)(ws + take((size_t)N * N_CLASS * 4));
    float* yout   = (float*)d_out;          // doubles as hop-1 buffer (fully rewritten later)

    // --- build CSR ---
    detect_kernel<<<1, 64, 0, stream>>>(ei, flag);
    zero_deg_kernel<<<(N + 255) / 256, 256, 0, stream>>>(deg, N);
    count_kernel<<<(E + 255) / 256, 256, 0, stream>>>(ei, E, flag, deg);
    scan_kernel<<<1, 1024, 0, stream>>>(deg, starts, cursor, dis, N);
    scatter_kernel<<<(E + 255) / 256, 256, 0, stream>>>(ei, E, flag, cursor, srcs);

    // --- transform then propagate (linear ops commute) ---
    const int nodeBlocks = (N * 64 + 255) / 256;    // one wave per node
    transform_kernel<<<nodeBlocks, 256, 0, stream>>>(feature, weight, ya, N);
    prop_kernel<<<nodeBlocks, 256, 0, stream>>>(ya, yout, starts, srcs, dis, N);   // hop 1 -> d_out
    prop_kernel<<<nodeBlocks, 256, 0, stream>>>(yout, ya, starts, srcs, dis, N);   // hop 2 -> ya
    final_kernel<<<nodeBlocks, 256, 0, stream>>>(ya, bias, yout, N);               // log_softmax -> d_out
}

// Round 2
// 587.595 us; speedup vs baseline: 1.8604x; 1.8604x over previous
//
#include <hip/hip_runtime.h>
#include <hip/hip_bf16.h>
#include <math.h>

// SGC: out = log_softmax( S^2 X W^T + b ), S = D^-1/2 (A+I) D^-1/2
// Transform first (X W^T -> 40 dims), build CSR via bucketed counting sort
// (dense coalesced writes, no random 4B scatters), gather propagation x2,
// then bias + log_softmax.

#define N_NODES 100000
#define N_FEAT  128
#define N_CLASS 40

#define NB     512            // dst buckets
#define RANGE  196            // dst ids per bucket (ceil(100000/512))
#define CAP    7168           // max in-LDS records per bucket (mean 6272 + 11 sigma)

// ---------------------------------------------------------------------------
// Edge-index: harness may hand us int32 or raw int64 words.
// If int64 (LE, values < 2^31), every odd 32-bit word is 0.
__global__ void detect_kernel(const int* __restrict__ ei, int* __restrict__ flag) {
    int lane = threadIdx.x;                 // 64 threads, 1 wave
    int nz = (ei[2 * lane + 1] != 0) ? 1 : 0;
    unsigned long long b = __ballot(nz);
    if (lane == 0) *flag = (b == 0ull) ? 1 : 0;   // 1 => int64 layout
}

__device__ __forceinline__ int edge_word(const int* ei, int elem, int is64) {
    return is64 ? ei[2 * elem] : ei[elem];
}

__global__ void zero_meta_kernel(int* __restrict__ bucketCount) {
    int i = threadIdx.x;
    if (i < NB) bucketCount[i] = 0;
}

// P1: per-bucket histogram, LDS-privatized.
__global__ __launch_bounds__(256) void p1_hist(
    const int* __restrict__ ei, int E, const int* __restrict__ flag,
    int* __restrict__ bucketCount)
{
    __shared__ int h[NB];
    for (int i = threadIdx.x; i < NB; i += 256) h[i] = 0;
    __syncthreads();
    int is64 = *flag;
    int stride = gridDim.x * 256;
    for (int e = blockIdx.x * 256 + threadIdx.x; e < E; e += stride) {
        int c = edge_word(ei, E + e, is64);
        atomicAdd(&h[c / RANGE], 1);
    }
    __syncthreads();
    for (int i = threadIdx.x; i < NB; i += 256)
        if (h[i]) atomicAdd(&bucketCount[i], h[i]);
}

// P2: scan bucket counts -> bucketStart/bucketCursor; starts[N]=E.
__global__ __launch_bounds__(NB) void p2_scan(
    const int* __restrict__ bucketCount, int* __restrict__ bucketStart,
    int* __restrict__ bucketCursor, int* __restrict__ starts, int E)
{
    __shared__ int s[NB];
    int t = threadIdx.x;
    int v = bucketCount[t];
    s[t] = v;
    __syncthreads();
    for (int o = 1; o < NB; o <<= 1) {
        int y = (t >= o) ? s[t - o] : 0;
        __syncthreads();
        s[t] += y;
        __syncthreads();
    }
    int incl = s[t], excl = incl - v;
    bucketStart[t] = excl;
    bucketCursor[t] = excl;
    if (t == NB - 1) { bucketStart[NB] = incl; starts[N_NODES] = E; }
}

// P3: chunked scatter of packed records (dstLocal<<24 | src) into per-block
// dense runs within each bucket (writes are line-coalesced).
__global__ __launch_bounds__(256) void p3_scatter(
    const int* __restrict__ ei, int E, const int* __restrict__ flag,
    int* __restrict__ bucketCursor, unsigned int* __restrict__ tmp)
{
    __shared__ int h[NB];
    __shared__ int base[NB];
    __shared__ int cur[NB];
    for (int i = threadIdx.x; i < NB; i += 256) h[i] = 0;
    __syncthreads();
    int is64 = *flag;
    int per = (E + gridDim.x - 1) / gridDim.x;
    int e0 = blockIdx.x * per;
    int e1 = min(E, e0 + per);
    for (int e = e0 + threadIdx.x; e < e1; e += 256) {
        int c = edge_word(ei, E + e, is64);
        atomicAdd(&h[c / RANGE], 1);
    }
    __syncthreads();
    for (int i = threadIdx.x; i < NB; i += 256) {
        base[i] = h[i] ? atomicAdd(&bucketCursor[i], h[i]) : 0;
        cur[i] = 0;
    }
    __syncthreads();
    for (int e = e0 + threadIdx.x; e < e1; e += 256) {
        int c = edge_word(ei, E + e, is64);
        int r = edge_word(ei, e, is64);
        int b = c / RANGE;
        int p = base[b] + atomicAdd(&cur[b], 1);
        tmp[p] = ((unsigned)(c - b * RANGE) << 24) | (unsigned)r;
    }
}

// P4: per-bucket LDS counting sort -> starts, dis, coalesced srcs.
__global__ __launch_bounds__(256) void p4_sort(
    const unsigned int* __restrict__ tmp, const int* __restrict__ bucketStart,
    int* __restrict__ starts, float* __restrict__ dis, int* __restrict__ srcs, int N)
{
    __shared__ unsigned int rec[CAP];
    __shared__ int srt[CAP];
    __shared__ int hist[256];
    __shared__ int sc[256];
    __shared__ int cur[256];
    int b = blockIdx.x, t = threadIdx.x;
    int g0 = b * RANGE;
    int gcnt = N - g0;
    if (gcnt > RANGE) gcnt = RANGE;
    if (gcnt < 0) gcnt = 0;
    int base = bucketStart[b];
    int n = bucketStart[b + 1] - base;
    hist[t] = 0;
    __syncthreads();
    bool inl = (n <= CAP);
    if (inl) {
        for (int i = t; i < n; i += 256) {
            unsigned v = tmp[base + i];
            rec[i] = v;
            atomicAdd(&hist[v >> 24], 1);
        }
    } else {
        for (int i = t; i < n; i += 256) {
            unsigned v = tmp[base + i];
            atomicAdd(&hist[v >> 24], 1);
        }
    }
    __syncthreads();
    int hv = hist[t];
    sc[t] = hv;
    __syncthreads();
    for (int o = 1; o < 256; o <<= 1) {
        int y = (t >= o) ? sc[t - o] : 0;
        __syncthreads();
        sc[t] += y;
        __syncthreads();
    }
    int excl = sc[t] - hv;
    if (t < gcnt) {
        starts[g0 + t] = base + excl;
        dis[g0 + t] = rsqrtf((float)(hv + 1));   // +1 self-loop
    }
    cur[t] = excl;
    __syncthreads();
    if (inl) {
        for (int i = t; i < n; i += 256) {
            unsigned v = rec[i];
            int p = atomicAdd(&cur[v >> 24], 1);
            srt[p] = (int)(v & 0xFFFFFFu);
        }
        __syncthreads();
        for (int i = t; i < n; i += 256) srcs[base + i] = srt[i];
    } else {
        // overflow fallback (statistically never taken): global re-read path
        for (int i = t; i < n; i += 256) {
            unsigned v = tmp[base + i];
            int p = atomicAdd(&cur[v >> 24], 1);
            srcs[base + p] = (int)(v & 0xFFFFFFu);
        }
    }
}

// ---------------------------------------------------------------------------
// y0 = X @ W^T  (one wave per node; W transposed into LDS)
__global__ __launch_bounds__(256) void transform_kernel(
    const float* __restrict__ x, const float* __restrict__ W,
    float* __restrict__ y, int N)
{
    __shared__ float Wt[N_FEAT * N_CLASS];  // Wt[f*40 + c], 20 KiB
    for (int i = threadIdx.x; i < N_FEAT * N_CLASS; i += blockDim.x) {
        int cls = i / N_FEAT, f = i % N_FEAT;
        Wt[f * N_CLASS + cls] = W[i];
    }
    __syncthreads();
    int wave = (blockIdx.x * blockDim.x + threadIdx.x) >> 6;
    int lane = threadIdx.x & 63;
    if (wave >= N) return;
    int cc = lane < N_CLASS ? lane : N_CLASS - 1;   // clamp idle lanes
    const float4* xr = reinterpret_cast<const float4*>(x + (size_t)wave * N_FEAT);
    float acc = 0.f;
    #pragma unroll
    for (int f4 = 0; f4 < N_FEAT / 4; ++f4) {
        float4 v = xr[f4];                  // wave-uniform address -> broadcast
        int f = f4 * 4;
        acc += v.x * Wt[(f    ) * N_CLASS + cc];
        acc += v.y * Wt[(f + 1) * N_CLASS + cc];
        acc += v.z * Wt[(f + 2) * N_CLASS + cc];
        acc += v.w * Wt[(f + 3) * N_CLASS + cc];
    }
    if (lane < N_CLASS) y[(size_t)wave * N_CLASS + lane] = acc;
}

// One hop: yout[d] = dis[d] * sum_{e:col=d} dis[src]*yin[src] + dis[d]^2*yin[d]
__global__ __launch_bounds__(256) void prop_kernel(
    const float* __restrict__ yin, float* __restrict__ yout,
    const int* __restrict__ starts, const int* __restrict__ srcs,
    const float* __restrict__ dis, int N)
{
    int wave = (blockIdx.x * blockDim.x + threadIdx.x) >> 6;
    int lane = threadIdx.x & 63;
    if (wave >= N) return;
    int d = wave;
    int cc = lane < N_CLASS ? lane : N_CLASS - 1;
    float dd = dis[d];
    float self = yin[(size_t)d * N_CLASS + cc];
    int e = starts[d], e1 = starts[d + 1];
    float acc = 0.f;
    for (; e + 3 < e1; e += 4) {
        int sa = srcs[e], sb = srcs[e + 1], sc2 = srcs[e + 2], sd = srcs[e + 3];
        float wa = dis[sa], wb = dis[sb], wc = dis[sc2], wd = dis[sd];
        float xa = yin[(size_t)sa * N_CLASS + cc];
        float xb = yin[(size_t)sb * N_CLASS + cc];
        float xc = yin[(size_t)sc2 * N_CLASS + cc];
        float xd = yin[(size_t)sd * N_CLASS + cc];
        acc += wa * xa; acc += wb * xb; acc += wc * xc; acc += wd * xd;
    }
    for (; e < e1; ++e) {
        int sa = srcs[e];
        acc += dis[sa] * yin[(size_t)sa * N_CLASS + cc];
    }
    if (lane < N_CLASS)
        yout[(size_t)d * N_CLASS + lane] = dd * acc + dd * dd * self;
}

// out = log_softmax(y + bias) per node (one wave per node)
__global__ __launch_bounds__(256) void final_kernel(
    const float* __restrict__ y, const float* __restrict__ bias,
    float* __restrict__ out, int N)
{
    int wave = (blockIdx.x * blockDim.x + threadIdx.x) >> 6;
    int lane = threadIdx.x & 63;
    if (wave >= N) return;
    float v = (lane < N_CLASS) ? (y[(size_t)wave * N_CLASS + lane] + bias[lane]) : -INFINITY;
    float m = v;
    #pragma unroll
    for (int o = 32; o; o >>= 1) m = fmaxf(m, __shfl_xor(m, o, 64));
    float ex = (lane < N_CLASS) ? expf(v - m) : 0.f;
    float s = ex;
    #pragma unroll
    for (int o = 32; o; o >>= 1) s += __shfl_xor(s, o, 64);
    if (lane < N_CLASS)
        out[(size_t)wave * N_CLASS + lane] = v - m - logf(s);
}

// ---------------------------------------------------------------------------
extern "C" void kernel_launch(void* const* d_in, const int* in_sizes, int n_in,
                              void* d_out, int out_size, void* d_ws, size_t ws_size,
                              hipStream_t stream) {
    const float* feature = (const float*)d_in[0];   // [N, 128]
    const float* weight  = (const float*)d_in[1];   // [40, 128]
    const float* bias    = (const float*)d_in[2];   // [40]
    const int*   ei      = (const int*)d_in[3];     // [2, E] (int32 or int64 words)
    const int N = N_NODES;
    const int E = in_sizes[3] / 2;

    size_t off = 0;
    auto take = [&](size_t bytes) { size_t o = off; off += (bytes + 255) & ~(size_t)255; return o; };
    char* ws = (char*)d_ws;
    int*   flag    = (int*)  (ws + take(4));
    int*   bCount  = (int*)  (ws + take((size_t)NB * 4));
    int*   bStart  = (int*)  (ws + take((size_t)(NB + 1) * 4));
    int*   bCursor = (int*)  (ws + take((size_t)NB * 4));
    int*   starts  = (int*)  (ws + take((size_t)(N + 1) * 4));
    float* dis     = (float*)(ws + take((size_t)N * 4));
    int*   srcs    = (int*)  (ws + take((size_t)E * 4));
    float* ya      = (float*)(ws + take((size_t)N * N_CLASS * 4));
    unsigned int* tmp = (unsigned int*)ya;  // alias: tmp dead before transform writes ya
    float* yout = (float*)d_out;            // doubles as hop-1 buffer (rewritten by final)

    // --- build CSR (bucketed counting sort, coalesced writes) ---
    detect_kernel<<<1, 64, 0, stream>>>(ei, flag);
    zero_meta_kernel<<<1, NB, 0, stream>>>(bCount);
    p1_hist<<<256, 256, 0, stream>>>(ei, E, flag, bCount);
    p2_scan<<<1, NB, 0, stream>>>(bCount, bStart, bCursor, starts, E);
    p3_scatter<<<128, 256, 0, stream>>>(ei, E, flag, bCursor, tmp);
    p4_sort<<<NB, 256, 0, stream>>>(tmp, bStart, starts, dis, srcs, N);

    // --- transform then propagate (linear ops commute) ---
    const int nodeBlocks = (N * 64 + 255) / 256;    // one wave per node
    transform_kernel<<<nodeBlocks, 256, 0, stream>>>(feature, weight, ya, N);
    prop_kernel<<<nodeBlocks, 256, 0, stream>>>(ya, yout, starts, srcs, dis, N);   // hop 1 -> d_out
    prop_kernel<<<nodeBlocks, 256, 0, stream>>>(yout, ya, starts, srcs, dis, N);   // hop 2 -> ya
    final_kernel<<<nodeBlocks, 256, 0, stream>>>(ya, bias, yout, N);               // log_softmax -> d_out
}

// Round 3
// 473.805 us; speedup vs baseline: 2.3072x; 1.2402x over previous
//
#include <hip/hip_runtime.h>
#include <hip/hip_bf16.h>
#include <math.h>

// SGC: out = log_softmax( S^2 X W^T + b ), S = D^-1/2 (A+I) D^-1/2
// Transform first via MFMA bf16 (X W^T -> 40 dims), build CSR via bucketed
// counting sort (dense coalesced writes), gather propagation x2 (hop 2 fused
// with bias + log_softmax).

#define N_NODES 100000
#define N_FEAT  128
#define N_CLASS 40

#define NB     512            // dst buckets
#define RANGE  196            // dst ids per bucket (ceil(100000/512))
#define CAP    7168           // max in-LDS records per bucket (mean 6272 + 11 sigma)

typedef __attribute__((ext_vector_type(8))) short short8;   // 8 bf16 (4 VGPRs)
typedef __attribute__((ext_vector_type(4))) float floatx4;  // MFMA C/D

// ---------------------------------------------------------------------------
// Edge-index: harness may hand us int32 or raw int64 words.
// If int64 (LE, values < 2^31), every odd 32-bit word is 0.
__global__ void detect_kernel(const int* __restrict__ ei, int* __restrict__ flag) {
    int lane = threadIdx.x;                 // 64 threads, 1 wave
    int nz = (ei[2 * lane + 1] != 0) ? 1 : 0;
    unsigned long long b = __ballot(nz);
    if (lane == 0) *flag = (b == 0ull) ? 1 : 0;   // 1 => int64 layout
}

__device__ __forceinline__ int edge_word(const int* ei, int elem, int is64) {
    return is64 ? ei[2 * elem] : ei[elem];
}

__global__ void zero_meta_kernel(int* __restrict__ bucketCount) {
    int i = threadIdx.x;
    if (i < NB) bucketCount[i] = 0;
}

// P1: per-bucket histogram, LDS-privatized.
__global__ __launch_bounds__(256) void p1_hist(
    const int* __restrict__ ei, int E, const int* __restrict__ flag,
    int* __restrict__ bucketCount)
{
    __shared__ int h[NB];
    for (int i = threadIdx.x; i < NB; i += 256) h[i] = 0;
    __syncthreads();
    int is64 = *flag;
    int stride = gridDim.x * 256;
    for (int e = blockIdx.x * 256 + threadIdx.x; e < E; e += stride) {
        int c = edge_word(ei, E + e, is64);
        atomicAdd(&h[c / RANGE], 1);
    }
    __syncthreads();
    for (int i = threadIdx.x; i < NB; i += 256)
        if (h[i]) atomicAdd(&bucketCount[i], h[i]);
}

// P2: scan bucket counts -> bucketStart/bucketCursor; starts[N]=E.
__global__ __launch_bounds__(NB) void p2_scan(
    const int* __restrict__ bucketCount, int* __restrict__ bucketStart,
    int* __restrict__ bucketCursor, int* __restrict__ starts, int E)
{
    __shared__ int s[NB];
    int t = threadIdx.x;
    int v = bucketCount[t];
    s[t] = v;
    __syncthreads();
    for (int o = 1; o < NB; o <<= 1) {
        int y = (t >= o) ? s[t - o] : 0;
        __syncthreads();
        s[t] += y;
        __syncthreads();
    }
    int incl = s[t], excl = incl - v;
    bucketStart[t] = excl;
    bucketCursor[t] = excl;
    if (t == NB - 1) { bucketStart[NB] = incl; starts[N_NODES] = E; }
}

// P3: chunked scatter of packed records (dstLocal<<24 | src) into per-block
// dense runs within each bucket (writes are line-coalesced).
__global__ __launch_bounds__(256) void p3_scatter(
    const int* __restrict__ ei, int E, const int* __restrict__ flag,
    int* __restrict__ bucketCursor, unsigned int* __restrict__ tmp)
{
    __shared__ int h[NB];
    __shared__ int base[NB];
    __shared__ int cur[NB];
    for (int i = threadIdx.x; i < NB; i += 256) h[i] = 0;
    __syncthreads();
    int is64 = *flag;
    int per = (E + gridDim.x - 1) / gridDim.x;
    int e0 = blockIdx.x * per;
    int e1 = min(E, e0 + per);
    for (int e = e0 + threadIdx.x; e < e1; e += 256) {
        int c = edge_word(ei, E + e, is64);
        atomicAdd(&h[c / RANGE], 1);
    }
    __syncthreads();
    for (int i = threadIdx.x; i < NB; i += 256) {
        base[i] = h[i] ? atomicAdd(&bucketCursor[i], h[i]) : 0;
        cur[i] = 0;
    }
    __syncthreads();
    for (int e = e0 + threadIdx.x; e < e1; e += 256) {
        int c = edge_word(ei, E + e, is64);
        int r = edge_word(ei, e, is64);
        int b = c / RANGE;
        int p = base[b] + atomicAdd(&cur[b], 1);
        tmp[p] = ((unsigned)(c - b * RANGE) << 24) | (unsigned)r;
    }
}

// P4: per-bucket LDS counting sort -> starts, dis, coalesced srcs.
__global__ __launch_bounds__(256) void p4_sort(
    const unsigned int* __restrict__ tmp, const int* __restrict__ bucketStart,
    int* __restrict__ starts, float* __restrict__ dis, int* __restrict__ srcs, int N)
{
    __shared__ unsigned int rec[CAP];
    __shared__ int srt[CAP];
    __shared__ int hist[256];
    __shared__ int sc[256];
    __shared__ int cur[256];
    int b = blockIdx.x, t = threadIdx.x;
    int g0 = b * RANGE;
    int gcnt = N - g0;
    if (gcnt > RANGE) gcnt = RANGE;
    if (gcnt < 0) gcnt = 0;
    int base = bucketStart[b];
    int n = bucketStart[b + 1] - base;
    hist[t] = 0;
    __syncthreads();
    bool inl = (n <= CAP);
    if (inl) {
        for (int i = t; i < n; i += 256) {
            unsigned v = tmp[base + i];
            rec[i] = v;
            atomicAdd(&hist[v >> 24], 1);
        }
    } else {
        for (int i = t; i < n; i += 256) {
            unsigned v = tmp[base + i];
            atomicAdd(&hist[v >> 24], 1);
        }
    }
    __syncthreads();
    int hv = hist[t];
    sc[t] = hv;
    __syncthreads();
    for (int o = 1; o < 256; o <<= 1) {
        int y = (t >= o) ? sc[t - o] : 0;
        __syncthreads();
        sc[t] += y;
        __syncthreads();
    }
    int excl = sc[t] - hv;
    if (t < gcnt) {
        starts[g0 + t] = base + excl;
        dis[g0 + t] = rsqrtf((float)(hv + 1));   // +1 self-loop
    }
    cur[t] = excl;
    __syncthreads();
    if (inl) {
        for (int i = t; i < n; i += 256) {
            unsigned v = rec[i];
            int p = atomicAdd(&cur[v >> 24], 1);
            srt[p] = (int)(v & 0xFFFFFFu);
        }
        __syncthreads();
        for (int i = t; i < n; i += 256) srcs[base + i] = srt[i];
    } else {
        // overflow fallback (statistically never taken): global re-read path
        for (int i = t; i < n; i += 256) {
            unsigned v = tmp[base + i];
            int p = atomicAdd(&cur[v >> 24], 1);
            srcs[base + p] = (int)(v & 0xFFFFFFu);
        }
    }
}

// ---------------------------------------------------------------------------
__device__ __forceinline__ short f2bf(float f) {   // RTN f32 -> bf16
    unsigned u = __float_as_uint(f);
    unsigned r = u + 0x7FFFu + ((u >> 16) & 1u);
    return (short)(r >> 16);
}

// y = X @ W^T via mfma_f32_16x16x32_bf16. One wave per 16 nodes.
// A frag: lane holds A[m=lane&15][k = kc*32 + (lane>>4)*8 + j], j=0..7.
// B frag: lane holds B[k = kc*32 + (lane>>4)*8 + j][n = nt*16 + (lane&15)].
// C/D:    lane reg r -> row m=(lane>>4)*4+r, col n=lane&15.
__global__ __launch_bounds__(256) void transform_mfma(
    const float* __restrict__ x, const float* __restrict__ W,
    float* __restrict__ y, int N)
{
    __shared__ uint4 Wl[3 * 4 * 64];        // B frags, bf16-packed: 12 KiB
    int t = threadIdx.x;
    for (int i = t; i < 3 * 4 * 64; i += 256) {
        int lane = i & 63;
        int kc = (i >> 6) & 3;
        int nt = i >> 8;
        int n = nt * 16 + (lane & 15);
        int k = kc * 32 + (lane >> 4) * 8;
        union { short s[8]; uint4 v; } u;
        #pragma unroll
        for (int j = 0; j < 8; ++j)
            u.s[j] = (n < N_CLASS) ? f2bf(W[n * N_FEAT + k + j]) : (short)0;
        Wl[i] = u.v;
    }
    __syncthreads();
    int wave = (blockIdx.x * blockDim.x + threadIdx.x) >> 6;
    int lane = threadIdx.x & 63;
    int ntile = (N + 15) / 16;
    if (wave >= ntile) return;
    int m = lane & 15, quad = lane >> 4;
    int row = wave * 16 + m;                // N is a multiple of 16 (100000)
    const short8* Wf = reinterpret_cast<const short8*>(Wl);
    floatx4 acc0 = {0.f, 0.f, 0.f, 0.f}, acc1 = acc0, acc2 = acc0;
    #pragma unroll
    for (int kc = 0; kc < 4; ++kc) {
        const float4* xr = reinterpret_cast<const float4*>(
            x + (size_t)row * N_FEAT + kc * 32 + quad * 8);
        float4 a0 = xr[0], a1 = xr[1];
        short8 af;
        af[0] = f2bf(a0.x); af[1] = f2bf(a0.y); af[2] = f2bf(a0.z); af[3] = f2bf(a0.w);
        af[4] = f2bf(a1.x); af[5] = f2bf(a1.y); af[6] = f2bf(a1.z); af[7] = f2bf(a1.w);
        short8 b0 = Wf[(0 * 4 + kc) * 64 + lane];
        short8 b1 = Wf[(1 * 4 + kc) * 64 + lane];
        short8 b2 = Wf[(2 * 4 + kc) * 64 + lane];
        acc0 = __builtin_amdgcn_mfma_f32_16x16x32_bf16(af, b0, acc0, 0, 0, 0);
        acc1 = __builtin_amdgcn_mfma_f32_16x16x32_bf16(af, b1, acc1, 0, 0, 0);
        acc2 = __builtin_amdgcn_mfma_f32_16x16x32_bf16(af, b2, acc2, 0, 0, 0);
    }
    #pragma unroll
    for (int r = 0; r < 4; ++r) {
        int rm = quad * 4 + r;
        size_t rowoff = (size_t)(wave * 16 + rm) * N_CLASS;
        y[rowoff + m] = acc0[r];                         // n = m        (< 16)
        y[rowoff + 16 + m] = acc1[r];                    // n = 16 + m   (< 32)
        if (m < 8) y[rowoff + 32 + m] = acc2[r];         // n = 32 + m   (< 40)
    }
}

// One hop: yout[d] = dis[d] * sum_{e:col=d} dis[src]*yin[src] + dis[d]^2*yin[d]
__global__ __launch_bounds__(256) void prop_kernel(
    const float* __restrict__ yin, float* __restrict__ yout,
    const int* __restrict__ starts, const int* __restrict__ srcs,
    const float* __restrict__ dis, int N)
{
    int wave = (blockIdx.x * blockDim.x + threadIdx.x) >> 6;
    int lane = threadIdx.x & 63;
    if (wave >= N) return;
    int d = wave;
    int cc = lane < N_CLASS ? lane : N_CLASS - 1;
    float dd = dis[d];
    float self = yin[(size_t)d * N_CLASS + cc];
    int e = starts[d], e1 = starts[d + 1];
    float acc = 0.f;
    for (; e + 3 < e1; e += 4) {
        int sa = srcs[e], sb = srcs[e + 1], sc2 = srcs[e + 2], sd = srcs[e + 3];
        float wa = dis[sa], wb = dis[sb], wc = dis[sc2], wd = dis[sd];
        float xa = yin[(size_t)sa * N_CLASS + cc];
        float xb = yin[(size_t)sb * N_CLASS + cc];
        float xc = yin[(size_t)sc2 * N_CLASS + cc];
        float xd = yin[(size_t)sd * N_CLASS + cc];
        acc += wa * xa; acc += wb * xb; acc += wc * xc; acc += wd * xd;
    }
    for (; e < e1; ++e) {
        int sa = srcs[e];
        acc += dis[sa] * yin[(size_t)sa * N_CLASS + cc];
    }
    if (lane < N_CLASS)
        yout[(size_t)d * N_CLASS + lane] = dd * acc + dd * dd * self;
}

// Hop 2 fused with bias + log_softmax -> out.
__global__ __launch_bounds__(256) void prop_final_kernel(
    const float* __restrict__ yin, float* __restrict__ out,
    const int* __restrict__ starts, const int* __restrict__ srcs,
    const float* __restrict__ dis, const float* __restrict__ bias, int N)
{
    int wave = (blockIdx.x * blockDim.x + threadIdx.x) >> 6;
    int lane = threadIdx.x & 63;
    if (wave >= N) return;
    int d = wave;
    int cc = lane < N_CLASS ? lane : N_CLASS - 1;
    float dd = dis[d];
    float self = yin[(size_t)d * N_CLASS + cc];
    int e = starts[d], e1 = starts[d + 1];
    float acc = 0.f;
    for (; e + 3 < e1; e += 4) {
        int sa = srcs[e], sb = srcs[e + 1], sc2 = srcs[e + 2], sd = srcs[e + 3];
        float wa = dis[sa], wb = dis[sb], wc = dis[sc2], wd = dis[sd];
        float xa = yin[(size_t)sa * N_CLASS + cc];
        float xb = yin[(size_t)sb * N_CLASS + cc];
        float xc = yin[(size_t)sc2 * N_CLASS + cc];
        float xd = yin[(size_t)sd * N_CLASS + cc];
        acc += wa * xa; acc += wb * xb; acc += wc * xc; acc += wd * xd;
    }
    for (; e < e1; ++e) {
        int sa = srcs[e];
        acc += dis[sa] * yin[(size_t)sa * N_CLASS + cc];
    }
    float v = (lane < N_CLASS)
            ? (dd * acc + dd * dd * self + bias[lane]) : -INFINITY;
    float mx = v;
    #pragma unroll
    for (int o = 32; o; o >>= 1) mx = fmaxf(mx, __shfl_xor(mx, o, 64));
    float ex = (lane < N_CLASS) ? expf(v - mx) : 0.f;
    float s = ex;
    #pragma unroll
    for (int o = 32; o; o >>= 1) s += __shfl_xor(s, o, 64);
    if (lane < N_CLASS)
        out[(size_t)d * N_CLASS + lane] = v - mx - logf(s);
}

// ---------------------------------------------------------------------------
extern "C" void kernel_launch(void* const* d_in, const int* in_sizes, int n_in,
                              void* d_out, int out_size, void* d_ws, size_t ws_size,
                              hipStream_t stream) {
    const float* feature = (const float*)d_in[0];   // [N, 128]
    const float* weight  = (const float*)d_in[1];   // [40, 128]
    const float* bias    = (const float*)d_in[2];   // [40]
    const int*   ei      = (const int*)d_in[3];     // [2, E] (int32 or int64 words)
    const int N = N_NODES;
    const int E = in_sizes[3] / 2;

    size_t off = 0;
    auto take = [&](size_t bytes) { size_t o = off; off += (bytes + 255) & ~(size_t)255; return o; };
    char* ws = (char*)d_ws;
    int*   flag    = (int*)  (ws + take(4));
    int*   bCount  = (int*)  (ws + take((size_t)NB * 4));
    int*   bStart  = (int*)  (ws + take((size_t)(NB + 1) * 4));
    int*   bCursor = (int*)  (ws + take((size_t)NB * 4));
    int*   starts  = (int*)  (ws + take((size_t)(N + 1) * 4));
    float* dis     = (float*)(ws + take((size_t)N * 4));
    int*   srcs    = (int*)  (ws + take((size_t)E * 4));
    float* ya      = (float*)(ws + take((size_t)N * N_CLASS * 4));   // transform out / tmp alias
    float* yc      = (float*)(ws + take((size_t)N * N_CLASS * 4));   // hop-1 out
    unsigned int* tmp = (unsigned int*)ya;  // alias: tmp dead before transform writes ya

    // --- build CSR (bucketed counting sort, coalesced writes) ---
    detect_kernel<<<1, 64, 0, stream>>>(ei, flag);
    zero_meta_kernel<<<1, NB, 0, stream>>>(bCount);
    p1_hist<<<256, 256, 0, stream>>>(ei, E, flag, bCount);
    p2_scan<<<1, NB, 0, stream>>>(bCount, bStart, bCursor, starts, E);
    p3_scatter<<<128, 256, 0, stream>>>(ei, E, flag, bCursor, tmp);
    p4_sort<<<NB, 256, 0, stream>>>(tmp, bStart, starts, dis, srcs, N);

    // --- transform (MFMA) then propagate (linear ops commute) ---
    const int ntile = (N + 15) / 16;                       // 6250 row-tiles
    const int tblocks = (ntile * 64 + 255) / 256;          // 4 waves/block
    transform_mfma<<<tblocks, 256, 0, stream>>>(feature, weight, ya, N);
    const int nodeBlocks = (N * 64 + 255) / 256;           // one wave per node
    prop_kernel<<<nodeBlocks, 256, 0, stream>>>(ya, yc, starts, srcs, dis, N);      // hop 1
    prop_final_kernel<<<nodeBlocks, 256, 0, stream>>>(yc, (float*)d_out,
                                                      starts, srcs, dis, bias, N);  // hop 2 + softmax
}

// Round 4
// 383.569 us; speedup vs baseline: 2.8499x; 1.2353x over previous
//
#include <hip/hip_runtime.h>
#include <hip/hip_bf16.h>
#include <math.h>

// SGC: out = log_softmax( S^2 X W^T + b ), S = D^-1/2 (A+I) D^-1/2
// t0 = dis .* (X W^T) in bf16 (pre-scaled rows, 80 B each); each hop is
// y[d] = dis[d]*(t[d] + sum t[src]) with 6 row-gathers in flight per wave.
// CSR built via bucketed counting sort (dense coalesced writes).

#define N_NODES 100000
#define N_FEAT  128
#define N_CLASS 40

#define NB     512            // dst buckets
#define RANGE  196            // dst ids per bucket (ceil(100000/512))
#define CAP    7168           // max in-LDS records per bucket (mean 6272 + 11 sigma)

typedef __attribute__((ext_vector_type(8))) short short8;   // 8 bf16 (4 VGPRs)
typedef __attribute__((ext_vector_type(4))) float floatx4;  // MFMA C/D

// ---------------------------------------------------------------------------
// Edge-index: harness may hand us int32 or raw int64 words.
// If int64 (LE, values < 2^31), every odd 32-bit word is 0.
__global__ void detect_kernel(const int* __restrict__ ei, int* __restrict__ flag) {
    int lane = threadIdx.x;                 // 64 threads, 1 wave
    int nz = (ei[2 * lane + 1] != 0) ? 1 : 0;
    unsigned long long b = __ballot(nz);
    if (lane == 0) *flag = (b == 0ull) ? 1 : 0;   // 1 => int64 layout
}

__device__ __forceinline__ int edge_word(const int* ei, int elem, int is64) {
    return is64 ? ei[2 * elem] : ei[elem];
}

__global__ void zero_meta_kernel(int* __restrict__ bucketCount) {
    int i = threadIdx.x;
    if (i < NB) bucketCount[i] = 0;
}

// P1: per-bucket histogram, LDS-privatized.
__global__ __launch_bounds__(256) void p1_hist(
    const int* __restrict__ ei, int E, const int* __restrict__ flag,
    int* __restrict__ bucketCount)
{
    __shared__ int h[NB];
    for (int i = threadIdx.x; i < NB; i += 256) h[i] = 0;
    __syncthreads();
    int is64 = *flag;
    int stride = gridDim.x * 256;
    for (int e = blockIdx.x * 256 + threadIdx.x; e < E; e += stride) {
        int c = edge_word(ei, E + e, is64);
        atomicAdd(&h[c / RANGE], 1);
    }
    __syncthreads();
    for (int i = threadIdx.x; i < NB; i += 256)
        if (h[i]) atomicAdd(&bucketCount[i], h[i]);
}

// P2: scan bucket counts -> bucketStart/bucketCursor; starts[N]=E.
__global__ __launch_bounds__(NB) void p2_scan(
    const int* __restrict__ bucketCount, int* __restrict__ bucketStart,
    int* __restrict__ bucketCursor, int* __restrict__ starts, int E)
{
    __shared__ int s[NB];
    int t = threadIdx.x;
    int v = bucketCount[t];
    s[t] = v;
    __syncthreads();
    for (int o = 1; o < NB; o <<= 1) {
        int y = (t >= o) ? s[t - o] : 0;
        __syncthreads();
        s[t] += y;
        __syncthreads();
    }
    int incl = s[t], excl = incl - v;
    bucketStart[t] = excl;
    bucketCursor[t] = excl;
    if (t == NB - 1) { bucketStart[NB] = incl; starts[N_NODES] = E; }
}

// P3: chunked scatter of packed records (dstLocal<<24 | src) into per-block
// dense runs within each bucket (writes are line-coalesced).
__global__ __launch_bounds__(256) void p3_scatter(
    const int* __restrict__ ei, int E, const int* __restrict__ flag,
    int* __restrict__ bucketCursor, unsigned int* __restrict__ tmp)
{
    __shared__ int h[NB];
    __shared__ int base[NB];
    __shared__ int cur[NB];
    for (int i = threadIdx.x; i < NB; i += 256) h[i] = 0;
    __syncthreads();
    int is64 = *flag;
    int per = (E + gridDim.x - 1) / gridDim.x;
    int e0 = blockIdx.x * per;
    int e1 = min(E, e0 + per);
    for (int e = e0 + threadIdx.x; e < e1; e += 256) {
        int c = edge_word(ei, E + e, is64);
        atomicAdd(&h[c / RANGE], 1);
    }
    __syncthreads();
    for (int i = threadIdx.x; i < NB; i += 256) {
        base[i] = h[i] ? atomicAdd(&bucketCursor[i], h[i]) : 0;
        cur[i] = 0;
    }
    __syncthreads();
    for (int e = e0 + threadIdx.x; e < e1; e += 256) {
        int c = edge_word(ei, E + e, is64);
        int r = edge_word(ei, e, is64);
        int b = c / RANGE;
        int p = base[b] + atomicAdd(&cur[b], 1);
        tmp[p] = ((unsigned)(c - b * RANGE) << 24) | (unsigned)r;
    }
}

// P4: per-bucket LDS counting sort -> starts, dis, coalesced srcs.
__global__ __launch_bounds__(256) void p4_sort(
    const unsigned int* __restrict__ tmp, const int* __restrict__ bucketStart,
    int* __restrict__ starts, float* __restrict__ dis, int* __restrict__ srcs, int N)
{
    __shared__ unsigned int rec[CAP];
    __shared__ int srt[CAP];
    __shared__ int hist[256];
    __shared__ int sc[256];
    __shared__ int cur[256];
    int b = blockIdx.x, t = threadIdx.x;
    int g0 = b * RANGE;
    int gcnt = N - g0;
    if (gcnt > RANGE) gcnt = RANGE;
    if (gcnt < 0) gcnt = 0;
    int base = bucketStart[b];
    int n = bucketStart[b + 1] - base;
    hist[t] = 0;
    __syncthreads();
    bool inl = (n <= CAP);
    if (inl) {
        for (int i = t; i < n; i += 256) {
            unsigned v = tmp[base + i];
            rec[i] = v;
            atomicAdd(&hist[v >> 24], 1);
        }
    } else {
        for (int i = t; i < n; i += 256) {
            unsigned v = tmp[base + i];
            atomicAdd(&hist[v >> 24], 1);
        }
    }
    __syncthreads();
    int hv = hist[t];
    sc[t] = hv;
    __syncthreads();
    for (int o = 1; o < 256; o <<= 1) {
        int y = (t >= o) ? sc[t - o] : 0;
        __syncthreads();
        sc[t] += y;
        __syncthreads();
    }
    int excl = sc[t] - hv;
    if (t < gcnt) {
        starts[g0 + t] = base + excl;
        dis[g0 + t] = rsqrtf((float)(hv + 1));   // +1 self-loop
    }
    cur[t] = excl;
    __syncthreads();
    if (inl) {
        for (int i = t; i < n; i += 256) {
            unsigned v = rec[i];
            int p = atomicAdd(&cur[v >> 24], 1);
            srt[p] = (int)(v & 0xFFFFFFu);
        }
        __syncthreads();
        for (int i = t; i < n; i += 256) srcs[base + i] = srt[i];
    } else {
        // overflow fallback (statistically never taken): global re-read path
        for (int i = t; i < n; i += 256) {
            unsigned v = tmp[base + i];
            int p = atomicAdd(&cur[v >> 24], 1);
            srcs[base + p] = (int)(v & 0xFFFFFFu);
        }
    }
}

// ---------------------------------------------------------------------------
__device__ __forceinline__ unsigned short f2bf(float f) {   // RTN f32 -> bf16
    unsigned u = __float_as_uint(f);
    unsigned r = u + 0x7FFFu + ((u >> 16) & 1u);
    return (unsigned short)(r >> 16);
}
__device__ __forceinline__ float bf2f(unsigned short u) {
    return __uint_as_float(((unsigned)u) << 16);
}

// t0 = dis .* (X @ W^T), bf16, row stride 40 (80 B). One wave per 16 nodes.
// MFMA 16x16x32 bf16. A: lane m=lane&15, k=kc*32+(lane>>4)*8+j. B in LDS frags.
// C/D: reg r -> row (lane>>4)*4+r, col lane&15.
__global__ __launch_bounds__(256) void transform_mfma(
    const float* __restrict__ x, const float* __restrict__ W,
    const float* __restrict__ dis, unsigned short* __restrict__ t0, int N)
{
    __shared__ uint4 Wl[3 * 4 * 64];        // B frags, bf16-packed: 12 KiB
    int t = threadIdx.x;
    for (int i = t; i < 3 * 4 * 64; i += 256) {
        int lane = i & 63;
        int kc = (i >> 6) & 3;
        int nt = i >> 8;
        int n = nt * 16 + (lane & 15);
        int k = kc * 32 + (lane >> 4) * 8;
        union { unsigned short s[8]; uint4 v; } u;
        #pragma unroll
        for (int j = 0; j < 8; ++j)
            u.s[j] = (n < N_CLASS) ? f2bf(W[n * N_FEAT + k + j]) : (unsigned short)0;
        Wl[i] = u.v;
    }
    __syncthreads();
    int wave = (blockIdx.x * blockDim.x + threadIdx.x) >> 6;
    int lane = threadIdx.x & 63;
    int ntile = (N + 15) / 16;
    if (wave >= ntile) return;
    int m = lane & 15, quad = lane >> 4;
    int row = wave * 16 + m;                // N is a multiple of 16 (100000)
    const short8* Wf = reinterpret_cast<const short8*>(Wl);
    floatx4 acc0 = {0.f, 0.f, 0.f, 0.f}, acc1 = acc0, acc2 = acc0;
    #pragma unroll
    for (int kc = 0; kc < 4; ++kc) {
        const float4* xr = reinterpret_cast<const float4*>(
            x + (size_t)row * N_FEAT + kc * 32 + quad * 8);
        float4 a0 = xr[0], a1 = xr[1];
        short8 af;
        af[0] = f2bf(a0.x); af[1] = f2bf(a0.y); af[2] = f2bf(a0.z); af[3] = f2bf(a0.w);
        af[4] = f2bf(a1.x); af[5] = f2bf(a1.y); af[6] = f2bf(a1.z); af[7] = f2bf(a1.w);
        short8 b0 = Wf[(0 * 4 + kc) * 64 + lane];
        short8 b1 = Wf[(1 * 4 + kc) * 64 + lane];
        short8 b2 = Wf[(2 * 4 + kc) * 64 + lane];
        acc0 = __builtin_amdgcn_mfma_f32_16x16x32_bf16(af, b0, acc0, 0, 0, 0);
        acc1 = __builtin_amdgcn_mfma_f32_16x16x32_bf16(af, b1, acc1, 0, 0, 0);
        acc2 = __builtin_amdgcn_mfma_f32_16x16x32_bf16(af, b2, acc2, 0, 0, 0);
    }
    #pragma unroll
    for (int r = 0; r < 4; ++r) {
        int rw = wave * 16 + quad * 4 + r;
        float ds = dis[rw];
        unsigned short* tr = t0 + (size_t)rw * N_CLASS;
        tr[m] = f2bf(ds * acc0[r]);                      // n = m        (< 16)
        tr[16 + m] = f2bf(ds * acc1[r]);                 // n = 16 + m   (< 32)
        if (m < 8) tr[32 + m] = f2bf(ds * acc2[r]);      // n = 32 + m   (< 40)
    }
}

// Hop (pre-scaled): tout[d] = dis[d]^2 * ( t[d] + sum_{e:col=d} t[src] ), bf16.
// 6 edges per wave: group g=lane/10 handles edge e+g; sub-lane sl holds 4 classes.
__global__ __launch_bounds__(256) void prop_hop_kernel(
    const unsigned short* __restrict__ tin, unsigned short* __restrict__ tout,
    const int* __restrict__ starts, const int* __restrict__ srcs,
    const float* __restrict__ dis, int N)
{
    int wave = (blockIdx.x * blockDim.x + threadIdx.x) >> 6;
    int lane = threadIdx.x & 63;
    if (wave >= N) return;
    int d = wave;
    int g = lane / 10;                      // 0..6 (lanes 60-63: g=6, masked)
    int sl = lane - g * 10;                 // 0..9
    int e0 = starts[d], e1 = starts[d + 1];
    float dd = dis[d];
    float a0 = 0.f, a1 = 0.f, a2 = 0.f, a3 = 0.f;
    if (g == 0) {                           // self term t[d]
        ushort4 r = *reinterpret_cast<const ushort4*>(tin + (size_t)d * N_CLASS + sl * 4);
        a0 = bf2f(r.x); a1 = bf2f(r.y); a2 = bf2f(r.z); a3 = bf2f(r.w);
    }
    for (int e = e0; e < e1; e += 6) {
        int ee = e + g;
        int s = srcs[min(ee, e1 - 1)];      // safe index; masked below
        ushort4 r = *reinterpret_cast<const ushort4*>(tin + (size_t)s * N_CLASS + sl * 4);
        float mk = (ee < e1 && g < 6) ? 1.0f : 0.0f;
        a0 = fmaf(mk, bf2f(r.x), a0);
        a1 = fmaf(mk, bf2f(r.y), a1);
        a2 = fmaf(mk, bf2f(r.z), a2);
        a3 = fmaf(mk, bf2f(r.w), a3);
    }
    // fold groups 3,4,5 onto 0,1,2 then 1,2 onto 0 (lanes 0-9 end correct)
    a0 += __shfl(a0, lane + 30); a1 += __shfl(a1, lane + 30);
    a2 += __shfl(a2, lane + 30); a3 += __shfl(a3, lane + 30);
    float u0 = __shfl(a0, lane + 10), v0 = __shfl(a0, lane + 20);
    float u1 = __shfl(a1, lane + 10), v1 = __shfl(a1, lane + 20);
    float u2 = __shfl(a2, lane + 10), v2 = __shfl(a2, lane + 20);
    float u3 = __shfl(a3, lane + 10), v3 = __shfl(a3, lane + 20);
    a0 += u0 + v0; a1 += u1 + v1; a2 += u2 + v2; a3 += u3 + v3;
    if (lane < 10) {
        float sc = dd * dd;                 // dis[d] * (pre-scale for next hop)
        ushort4 o;
        o.x = f2bf(sc * a0); o.y = f2bf(sc * a1);
        o.z = f2bf(sc * a2); o.w = f2bf(sc * a3);
        *reinterpret_cast<ushort4*>(tout + (size_t)d * N_CLASS + lane * 4) = o;
    }
}

// Final hop fused with bias + log_softmax: out[d] = lsm( dis[d]*(t1[d]+sum t1[src]) + b )
__global__ __launch_bounds__(256) void prop_final_kernel(
    const unsigned short* __restrict__ tin, float* __restrict__ out,
    const int* __restrict__ starts, const int* __restrict__ srcs,
    const float* __restrict__ dis, const float* __restrict__ bias, int N)
{
    int wave = (blockIdx.x * blockDim.x + threadIdx.x) >> 6;
    int lane = threadIdx.x & 63;
    if (wave >= N) return;
    int d = wave;
    int g = lane / 10;
    int sl = lane - g * 10;
    int e0 = starts[d], e1 = starts[d + 1];
    float dd = dis[d];
    float a0 = 0.f, a1 = 0.f, a2 = 0.f, a3 = 0.f;
    if (g == 0) {
        ushort4 r = *reinterpret_cast<const ushort4*>(tin + (size_t)d * N_CLASS + sl * 4);
        a0 = bf2f(r.x); a1 = bf2f(r.y); a2 = bf2f(r.z); a3 = bf2f(r.w);
    }
    for (int e = e0; e < e1; e += 6) {
        int ee = e + g;
        int s = srcs[min(ee, e1 - 1)];
        ushort4 r = *reinterpret_cast<const ushort4*>(tin + (size_t)s * N_CLASS + sl * 4);
        float mk = (ee < e1 && g < 6) ? 1.0f : 0.0f;
        a0 = fmaf(mk, bf2f(r.x), a0);
        a1 = fmaf(mk, bf2f(r.y), a1);
        a2 = fmaf(mk, bf2f(r.z), a2);
        a3 = fmaf(mk, bf2f(r.w), a3);
    }
    a0 += __shfl(a0, lane + 30); a1 += __shfl(a1, lane + 30);
    a2 += __shfl(a2, lane + 30); a3 += __shfl(a3, lane + 30);
    float u0 = __shfl(a0, lane + 10), w0 = __shfl(a0, lane + 20);
    float u1 = __shfl(a1, lane + 10), w1 = __shfl(a1, lane + 20);
    float u2 = __shfl(a2, lane + 10), w2 = __shfl(a2, lane + 20);
    float u3 = __shfl(a3, lane + 10), w3 = __shfl(a3, lane + 20);
    a0 += u0 + w0; a1 += u1 + w1; a2 += u2 + w2; a3 += u3 + w3;
    // logits in lanes 0-9 (4 classes each)
    float4 b4 = reinterpret_cast<const float4*>(bias)[sl];   // sl<10 for all lanes
    float v0_ = dd * a0 + b4.x, v1_ = dd * a1 + b4.y;
    float v2_ = dd * a2 + b4.z, v3_ = dd * a3 + b4.w;
    float mx = (lane < 10) ? fmaxf(fmaxf(v0_, v1_), fmaxf(v2_, v3_)) : -INFINITY;
    #pragma unroll
    for (int o = 8; o; o >>= 1) mx = fmaxf(mx, __shfl_xor(mx, o));
    float sum = (lane < 10)
        ? (expf(v0_ - mx) + expf(v1_ - mx) + expf(v2_ - mx) + expf(v3_ - mx)) : 0.f;
    #pragma unroll
    for (int o = 8; o; o >>= 1) sum += __shfl_xor(sum, o);
    if (lane < 10) {
        float ls = mx + logf(sum);
        float4 o4 = make_float4(v0_ - ls, v1_ - ls, v2_ - ls, v3_ - ls);
        reinterpret_cast<float4*>(out + (size_t)d * N_CLASS)[lane] = o4;
    }
}

// ---------------------------------------------------------------------------
extern "C" void kernel_launch(void* const* d_in, const int* in_sizes, int n_in,
                              void* d_out, int out_size, void* d_ws, size_t ws_size,
                              hipStream_t stream) {
    const float* feature = (const float*)d_in[0];   // [N, 128]
    const float* weight  = (const float*)d_in[1];   // [40, 128]
    const float* bias    = (const float*)d_in[2];   // [40]
    const int*   ei      = (const int*)d_in[3];     // [2, E] (int32 or int64 words)
    const int N = N_NODES;
    const int E = in_sizes[3] / 2;

    size_t off = 0;
    auto take = [&](size_t bytes) { size_t o = off; off += (bytes + 255) & ~(size_t)255; return o; };
    char* ws = (char*)d_ws;
    int*   flag    = (int*)  (ws + take(4));
    int*   bCount  = (int*)  (ws + take((size_t)NB * 4));
    int*   bStart  = (int*)  (ws + take((size_t)(NB + 1) * 4));
    int*   bCursor = (int*)  (ws + take((size_t)NB * 4));
    int*   starts  = (int*)  (ws + take((size_t)(N + 1) * 4));
    float* dis     = (float*)(ws + take((size_t)N * 4));
    int*   srcs    = (int*)  (ws + take((size_t)E * 4));
    unsigned short* t0 = (unsigned short*)(ws + take((size_t)N * N_CLASS * 2)); // 8 MB
    unsigned short* t1 = (unsigned short*)(ws + take((size_t)N * N_CLASS * 2)); // 8 MB
    unsigned int* tmp = (unsigned int*)t0;  // alias spans t0+t1 (16 MB >= E*4);
                                            // tmp dead before transform writes t0

    // --- build CSR (bucketed counting sort, coalesced writes) ---
    detect_kernel<<<1, 64, 0, stream>>>(ei, flag);
    zero_meta_kernel<<<1, NB, 0, stream>>>(bCount);
    p1_hist<<<256, 256, 0, stream>>>(ei, E, flag, bCount);
    p2_scan<<<1, NB, 0, stream>>>(bCount, bStart, bCursor, starts, E);
    p3_scatter<<<128, 256, 0, stream>>>(ei, E, flag, bCursor, tmp);
    p4_sort<<<NB, 256, 0, stream>>>(tmp, bStart, starts, dis, srcs, N);

    // --- transform (MFMA, writes pre-scaled bf16 rows) then 2 hops ---
    const int ntile = (N + 15) / 16;                       // 6250 row-tiles
    const int tblocks = (ntile * 64 + 255) / 256;          // 4 waves/block
    transform_mfma<<<tblocks, 256, 0, stream>>>(feature, weight, dis, t0, N);
    const int nodeBlocks = (N * 64 + 255) / 256;           // one wave per node
    prop_hop_kernel<<<nodeBlocks, 256, 0, stream>>>(t0, t1, starts, srcs, dis, N);
    prop_final_kernel<<<nodeBlocks, 256, 0, stream>>>(t1, (float*)d_out,
                                                      starts, srcs, dis, bias, N);
}

// Round 5
// 370.163 us; speedup vs baseline: 2.9531x; 1.0362x over previous
//
#include <hip/hip_runtime.h>
#include <hip/hip_bf16.h>
#include <math.h>

// SGC: out = log_softmax( S^2 X W^T + b ), S = D^-1/2 (A+I) D^-1/2
// t0 = dis .* (X W^T) in bf16 (pre-scaled rows, 80 B each); each hop is
// y[d] = dis[d]*(t[d] + sum t[src]) with 6 row-gathers in flight per wave.
// CSR built via bucketed counting sort (dense coalesced writes).

#define N_NODES 100000
#define N_FEAT  128
#define N_CLASS 40

#define NB     512            // dst buckets
#define RANGE  196            // dst ids per bucket (ceil(100000/512))
#define CAP    7168           // max in-LDS records per bucket (mean 6250 + ~11 sigma)
#define P3GRID 1024           // scatter blocks (4/CU); run length ~6 recs/bucket/block

typedef __attribute__((ext_vector_type(8))) short short8;   // 8 bf16 (4 VGPRs)
typedef __attribute__((ext_vector_type(4))) float floatx4;  // MFMA C/D

// ---------------------------------------------------------------------------
// Edge-index: harness may hand us int32 or raw int64 words.
// If int64 (LE, values < 2^31), every odd 32-bit word is 0.
// Also zeroes bucketCount (merged launch).
__global__ void detect_zero_kernel(const int* __restrict__ ei, int* __restrict__ flag,
                                   int* __restrict__ bucketCount) {
    int t = threadIdx.x;                    // 512 threads
    if (t < NB) bucketCount[t] = 0;
    if (t < 64) {
        int nz = (ei[2 * t + 1] != 0) ? 1 : 0;
        unsigned long long b = __ballot(nz);
        if (t == 0) *flag = (b == 0ull) ? 1 : 0;   // 1 => int64 layout
    }
}

__device__ __forceinline__ int edge_word(const int* ei, int elem, int is64) {
    return is64 ? ei[2 * elem] : ei[elem];
}

// P1: per-bucket histogram, LDS-privatized.
__global__ __launch_bounds__(256) void p1_hist(
    const int* __restrict__ ei, int E, const int* __restrict__ flag,
    int* __restrict__ bucketCount)
{
    __shared__ int h[NB];
    for (int i = threadIdx.x; i < NB; i += 256) h[i] = 0;
    __syncthreads();
    int is64 = *flag;
    int stride = gridDim.x * 256;
    for (int e = blockIdx.x * 256 + threadIdx.x; e < E; e += stride) {
        int c = edge_word(ei, E + e, is64);
        atomicAdd(&h[c / RANGE], 1);
    }
    __syncthreads();
    for (int i = threadIdx.x; i < NB; i += 256)
        if (h[i]) atomicAdd(&bucketCount[i], h[i]);
}

// P2: scan bucket counts -> bucketStart/bucketCursor; starts[N]=E.
__global__ __launch_bounds__(NB) void p2_scan(
    const int* __restrict__ bucketCount, int* __restrict__ bucketStart,
    int* __restrict__ bucketCursor, int* __restrict__ starts, int E)
{
    __shared__ int s[NB];
    int t = threadIdx.x;
    int v = bucketCount[t];
    s[t] = v;
    __syncthreads();
    for (int o = 1; o < NB; o <<= 1) {
        int y = (t >= o) ? s[t - o] : 0;
        __syncthreads();
        s[t] += y;
        __syncthreads();
    }
    int incl = s[t], excl = incl - v;
    bucketStart[t] = excl;
    bucketCursor[t] = excl;
    if (t == NB - 1) { bucketStart[NB] = incl; starts[N_NODES] = E; }
}

// P3: chunked scatter of packed records (dstLocal<<24 | src) into per-block
// dense runs within each bucket (writes are line-coalesced).
__global__ __launch_bounds__(256) void p3_scatter(
    const int* __restrict__ ei, int E, const int* __restrict__ flag,
    int* __restrict__ bucketCursor, unsigned int* __restrict__ tmp)
{
    __shared__ int h[NB];
    __shared__ int base[NB];
    __shared__ int cur[NB];
    for (int i = threadIdx.x; i < NB; i += 256) h[i] = 0;
    __syncthreads();
    int is64 = *flag;
    int per = (E + gridDim.x - 1) / gridDim.x;
    int e0 = blockIdx.x * per;
    int e1 = min(E, e0 + per);
    for (int e = e0 + threadIdx.x; e < e1; e += 256) {
        int c = edge_word(ei, E + e, is64);
        atomicAdd(&h[c / RANGE], 1);
    }
    __syncthreads();
    for (int i = threadIdx.x; i < NB; i += 256) {
        base[i] = h[i] ? atomicAdd(&bucketCursor[i], h[i]) : 0;
        cur[i] = 0;
    }
    __syncthreads();
    for (int e = e0 + threadIdx.x; e < e1; e += 256) {
        int c = edge_word(ei, E + e, is64);
        int r = edge_word(ei, e, is64);
        int b = c / RANGE;
        int p = base[b] + atomicAdd(&cur[b], 1);
        tmp[p] = ((unsigned)(c - b * RANGE) << 24) | (unsigned)r;
    }
}

// P4: per-bucket LDS counting sort -> starts, dis, coalesced srcs.
__global__ __launch_bounds__(256) void p4_sort(
    const unsigned int* __restrict__ tmp, const int* __restrict__ bucketStart,
    int* __restrict__ starts, float* __restrict__ dis, int* __restrict__ srcs, int N)
{
    __shared__ unsigned int rec[CAP];
    __shared__ int srt[CAP];
    __shared__ int hist[256];
    __shared__ int sc[256];
    __shared__ int cur[256];
    int b = blockIdx.x, t = threadIdx.x;
    int g0 = b * RANGE;
    int gcnt = N - g0;
    if (gcnt > RANGE) gcnt = RANGE;
    if (gcnt < 0) gcnt = 0;
    int base = bucketStart[b];
    int n = bucketStart[b + 1] - base;
    hist[t] = 0;
    __syncthreads();
    bool inl = (n <= CAP);
    if (inl) {
        for (int i = t; i < n; i += 256) {
            unsigned v = tmp[base + i];
            rec[i] = v;
            atomicAdd(&hist[v >> 24], 1);
        }
    } else {
        for (int i = t; i < n; i += 256) {
            unsigned v = tmp[base + i];
            atomicAdd(&hist[v >> 24], 1);
        }
    }
    __syncthreads();
    int hv = hist[t];
    sc[t] = hv;
    __syncthreads();
    for (int o = 1; o < 256; o <<= 1) {
        int y = (t >= o) ? sc[t - o] : 0;
        __syncthreads();
        sc[t] += y;
        __syncthreads();
    }
    int excl = sc[t] - hv;
    if (t < gcnt) {
        starts[g0 + t] = base + excl;
        dis[g0 + t] = rsqrtf((float)(hv + 1));   // +1 self-loop
    }
    cur[t] = excl;
    __syncthreads();
    if (inl) {
        for (int i = t; i < n; i += 256) {
            unsigned v = rec[i];
            int p = atomicAdd(&cur[v >> 24], 1);
            srt[p] = (int)(v & 0xFFFFFFu);
        }
        __syncthreads();
        for (int i = t; i < n; i += 256) srcs[base + i] = srt[i];
    } else {
        // overflow fallback (statistically never taken): global re-read path
        for (int i = t; i < n; i += 256) {
            unsigned v = tmp[base + i];
            int p = atomicAdd(&cur[v >> 24], 1);
            srcs[base + p] = (int)(v & 0xFFFFFFu);
        }
    }
}

// ---------------------------------------------------------------------------
__device__ __forceinline__ unsigned short f2bf(float f) {   // RTN f32 -> bf16
    unsigned u = __float_as_uint(f);
    unsigned r = u + 0x7FFFu + ((u >> 16) & 1u);
    return (unsigned short)(r >> 16);
}
__device__ __forceinline__ float bf2f(unsigned short u) {
    return __uint_as_float(((unsigned)u) << 16);
}

// t0 = dis .* (X @ W^T), bf16, row stride 40 (80 B). One wave per 16 nodes.
// MFMA 16x16x32 bf16. A: lane m=lane&15, k=kc*32+(lane>>4)*8+j. B in LDS frags.
// C/D: reg r -> row (lane>>4)*4+r, col lane&15.
__global__ __launch_bounds__(256) void transform_mfma(
    const float* __restrict__ x, const float* __restrict__ W,
    const float* __restrict__ dis, unsigned short* __restrict__ t0, int N)
{
    __shared__ uint4 Wl[3 * 4 * 64];        // B frags, bf16-packed: 12 KiB
    int t = threadIdx.x;
    for (int i = t; i < 3 * 4 * 64; i += 256) {
        int lane = i & 63;
        int kc = (i >> 6) & 3;
        int nt = i >> 8;
        int n = nt * 16 + (lane & 15);
        int k = kc * 32 + (lane >> 4) * 8;
        union { unsigned short s[8]; uint4 v; } u;
        #pragma unroll
        for (int j = 0; j < 8; ++j)
            u.s[j] = (n < N_CLASS) ? f2bf(W[n * N_FEAT + k + j]) : (unsigned short)0;
        Wl[i] = u.v;
    }
    __syncthreads();
    int wave = (blockIdx.x * blockDim.x + threadIdx.x) >> 6;
    int lane = threadIdx.x & 63;
    int ntile = (N + 15) / 16;
    if (wave >= ntile) return;
    int m = lane & 15, quad = lane >> 4;
    int row = wave * 16 + m;                // N is a multiple of 16 (100000)
    const short8* Wf = reinterpret_cast<const short8*>(Wl);
    floatx4 acc0 = {0.f, 0.f, 0.f, 0.f}, acc1 = acc0, acc2 = acc0;
    #pragma unroll
    for (int kc = 0; kc < 4; ++kc) {
        const float4* xr = reinterpret_cast<const float4*>(
            x + (size_t)row * N_FEAT + kc * 32 + quad * 8);
        float4 a0 = xr[0], a1 = xr[1];
        short8 af;
        af[0] = f2bf(a0.x); af[1] = f2bf(a0.y); af[2] = f2bf(a0.z); af[3] = f2bf(a0.w);
        af[4] = f2bf(a1.x); af[5] = f2bf(a1.y); af[6] = f2bf(a1.z); af[7] = f2bf(a1.w);
        short8 b0 = Wf[(0 * 4 + kc) * 64 + lane];
        short8 b1 = Wf[(1 * 4 + kc) * 64 + lane];
        short8 b2 = Wf[(2 * 4 + kc) * 64 + lane];
        acc0 = __builtin_amdgcn_mfma_f32_16x16x32_bf16(af, b0, acc0, 0, 0, 0);
        acc1 = __builtin_amdgcn_mfma_f32_16x16x32_bf16(af, b1, acc1, 0, 0, 0);
        acc2 = __builtin_amdgcn_mfma_f32_16x16x32_bf16(af, b2, acc2, 0, 0, 0);
    }
    #pragma unroll
    for (int r = 0; r < 4; ++r) {
        int rw = wave * 16 + quad * 4 + r;
        float ds = dis[rw];
        unsigned short* tr = t0 + (size_t)rw * N_CLASS;
        tr[m] = f2bf(ds * acc0[r]);                      // n = m        (< 16)
        tr[16 + m] = f2bf(ds * acc1[r]);                 // n = 16 + m   (< 32)
        if (m < 8) tr[32 + m] = f2bf(ds * acc2[r]);      // n = 32 + m   (< 40)
    }
}

// Hop (pre-scaled): tout[d] = dis[d]^2 * ( t[d] + sum_{e:col=d} t[src] ), bf16.
// 6 edges per wave: group g=lane/10 handles edge e+g; sub-lane sl holds 4 classes.
__global__ __launch_bounds__(256) void prop_hop_kernel(
    const unsigned short* __restrict__ tin, unsigned short* __restrict__ tout,
    const int* __restrict__ starts, const int* __restrict__ srcs,
    const float* __restrict__ dis, int N)
{
    int wave = (blockIdx.x * blockDim.x + threadIdx.x) >> 6;
    int lane = threadIdx.x & 63;
    if (wave >= N) return;
    int d = wave;
    int g = lane / 10;                      // 0..6 (lanes 60-63: g=6, masked)
    int sl = lane - g * 10;                 // 0..9
    int e0 = starts[d], e1 = starts[d + 1];
    float dd = dis[d];
    float a0 = 0.f, a1 = 0.f, a2 = 0.f, a3 = 0.f;
    if (g == 0) {                           // self term t[d]
        ushort4 r = *reinterpret_cast<const ushort4*>(tin + (size_t)d * N_CLASS + sl * 4);
        a0 = bf2f(r.x); a1 = bf2f(r.y); a2 = bf2f(r.z); a3 = bf2f(r.w);
    }
    for (int e = e0; e < e1; e += 6) {
        int ee = e + g;
        int s = srcs[min(ee, e1 - 1)];      // safe index; masked below
        ushort4 r = *reinterpret_cast<const ushort4*>(tin + (size_t)s * N_CLASS + sl * 4);
        float mk = (ee < e1 && g < 6) ? 1.0f : 0.0f;
        a0 = fmaf(mk, bf2f(r.x), a0);
        a1 = fmaf(mk, bf2f(r.y), a1);
        a2 = fmaf(mk, bf2f(r.z), a2);
        a3 = fmaf(mk, bf2f(r.w), a3);
    }
    // fold groups 3,4,5 onto 0,1,2 then 1,2 onto 0 (lanes 0-9 end correct)
    a0 += __shfl(a0, lane + 30); a1 += __shfl(a1, lane + 30);
    a2 += __shfl(a2, lane + 30); a3 += __shfl(a3, lane + 30);
    float u0 = __shfl(a0, lane + 10), v0 = __shfl(a0, lane + 20);
    float u1 = __shfl(a1, lane + 10), v1 = __shfl(a1, lane + 20);
    float u2 = __shfl(a2, lane + 10), v2 = __shfl(a2, lane + 20);
    float u3 = __shfl(a3, lane + 10), v3 = __shfl(a3, lane + 20);
    a0 += u0 + v0; a1 += u1 + v1; a2 += u2 + v2; a3 += u3 + v3;
    if (lane < 10) {
        float sc = dd * dd;                 // dis[d] * (pre-scale for next hop)
        ushort4 o;
        o.x = f2bf(sc * a0); o.y = f2bf(sc * a1);
        o.z = f2bf(sc * a2); o.w = f2bf(sc * a3);
        *reinterpret_cast<ushort4*>(tout + (size_t)d * N_CLASS + lane * 4) = o;
    }
}

// Final hop fused with bias + log_softmax: out[d] = lsm( dis[d]*(t1[d]+sum t1[src]) + b )
__global__ __launch_bounds__(256) void prop_final_kernel(
    const unsigned short* __restrict__ tin, float* __restrict__ out,
    const int* __restrict__ starts, const int* __restrict__ srcs,
    const float* __restrict__ dis, const float* __restrict__ bias, int N)
{
    int wave = (blockIdx.x * blockDim.x + threadIdx.x) >> 6;
    int lane = threadIdx.x & 63;
    if (wave >= N) return;
    int d = wave;
    int g = lane / 10;
    int sl = lane - g * 10;
    int e0 = starts[d], e1 = starts[d + 1];
    float dd = dis[d];
    float a0 = 0.f, a1 = 0.f, a2 = 0.f, a3 = 0.f;
    if (g == 0) {
        ushort4 r = *reinterpret_cast<const ushort4*>(tin + (size_t)d * N_CLASS + sl * 4);
        a0 = bf2f(r.x); a1 = bf2f(r.y); a2 = bf2f(r.z); a3 = bf2f(r.w);
    }
    for (int e = e0; e < e1; e += 6) {
        int ee = e + g;
        int s = srcs[min(ee, e1 - 1)];
        ushort4 r = *reinterpret_cast<const ushort4*>(tin + (size_t)s * N_CLASS + sl * 4);
        float mk = (ee < e1 && g < 6) ? 1.0f : 0.0f;
        a0 = fmaf(mk, bf2f(r.x), a0);
        a1 = fmaf(mk, bf2f(r.y), a1);
        a2 = fmaf(mk, bf2f(r.z), a2);
        a3 = fmaf(mk, bf2f(r.w), a3);
    }
    a0 += __shfl(a0, lane + 30); a1 += __shfl(a1, lane + 30);
    a2 += __shfl(a2, lane + 30); a3 += __shfl(a3, lane + 30);
    float u0 = __shfl(a0, lane + 10), w0 = __shfl(a0, lane + 20);
    float u1 = __shfl(a1, lane + 10), w1 = __shfl(a1, lane + 20);
    float u2 = __shfl(a2, lane + 10), w2 = __shfl(a2, lane + 20);
    float u3 = __shfl(a3, lane + 10), w3 = __shfl(a3, lane + 20);
    a0 += u0 + w0; a1 += u1 + w1; a2 += u2 + w2; a3 += u3 + w3;
    // logits in lanes 0-9 (4 classes each)
    float4 b4 = reinterpret_cast<const float4*>(bias)[sl];   // sl<10 for all lanes
    float v0_ = dd * a0 + b4.x, v1_ = dd * a1 + b4.y;
    float v2_ = dd * a2 + b4.z, v3_ = dd * a3 + b4.w;
    float mx = (lane < 10) ? fmaxf(fmaxf(v0_, v1_), fmaxf(v2_, v3_)) : -INFINITY;
    #pragma unroll
    for (int o = 8; o; o >>= 1) mx = fmaxf(mx, __shfl_xor(mx, o));
    float sum = (lane < 10)
        ? (expf(v0_ - mx) + expf(v1_ - mx) + expf(v2_ - mx) + expf(v3_ - mx)) : 0.f;
    #pragma unroll
    for (int o = 8; o; o >>= 1) sum += __shfl_xor(sum, o);
    if (lane < 10) {
        float ls = mx + logf(sum);
        float4 o4 = make_float4(v0_ - ls, v1_ - ls, v2_ - ls, v3_ - ls);
        reinterpret_cast<float4*>(out + (size_t)d * N_CLASS)[lane] = o4;
    }
}

// ---------------------------------------------------------------------------
extern "C" void kernel_launch(void* const* d_in, const int* in_sizes, int n_in,
                              void* d_out, int out_size, void* d_ws, size_t ws_size,
                              hipStream_t stream) {
    const float* feature = (const float*)d_in[0];   // [N, 128]
    const float* weight  = (const float*)d_in[1];   // [40, 128]
    const float* bias    = (const float*)d_in[2];   // [40]
    const int*   ei      = (const int*)d_in[3];     // [2, E] (int32 or int64 words)
    const int N = N_NODES;
    const int E = in_sizes[3] / 2;

    size_t off = 0;
    auto take = [&](size_t bytes) { size_t o = off; off += (bytes + 255) & ~(size_t)255; return o; };
    char* ws = (char*)d_ws;
    int*   flag    = (int*)  (ws + take(4));
    int*   bCount  = (int*)  (ws + take((size_t)NB * 4));
    int*   bStart  = (int*)  (ws + take((size_t)(NB + 1) * 4));
    int*   bCursor = (int*)  (ws + take((size_t)NB * 4));
    int*   starts  = (int*)  (ws + take((size_t)(N + 1) * 4));
    float* dis     = (float*)(ws + take((size_t)N * 4));
    int*   srcs    = (int*)  (ws + take((size_t)E * 4));
    unsigned short* t0 = (unsigned short*)(ws + take((size_t)N * N_CLASS * 2)); // 8 MB
    unsigned short* t1 = (unsigned short*)(ws + take((size_t)N * N_CLASS * 2)); // 8 MB
    unsigned int* tmp = (unsigned int*)t0;  // alias spans t0+t1 (16 MB >= E*4);
                                            // tmp dead before transform writes t0

    // --- build CSR (bucketed counting sort, coalesced writes) ---
    detect_zero_kernel<<<1, 512, 0, stream>>>(ei, flag, bCount);
    p1_hist<<<512, 256, 0, stream>>>(ei, E, flag, bCount);
    p2_scan<<<1, NB, 0, stream>>>(bCount, bStart, bCursor, starts, E);
    p3_scatter<<<P3GRID, 256, 0, stream>>>(ei, E, flag, bCursor, tmp);
    p4_sort<<<NB, 256, 0, stream>>>(tmp, bStart, starts, dis, srcs, N);

    // --- transform (MFMA, writes pre-scaled bf16 rows) then 2 hops ---
    const int ntile = (N + 15) / 16;                       // 6250 row-tiles
    const int tblocks = (ntile * 64 + 255) / 256;          // 4 waves/block
    transform_mfma<<<tblocks, 256, 0, stream>>>(feature, weight, dis, t0, N);
    const int nodeBlocks = (N * 64 + 255) / 256;           // one wave per node
    prop_hop_kernel<<<nodeBlocks, 256, 0, stream>>>(t0, t1, starts, srcs, dis, N);
    prop_final_kernel<<<nodeBlocks, 256, 0, stream>>>(t1, (float*)d_out,
                                                      starts, srcs, dis, bias, N);
}